// Round 7
// baseline (492.200 us; speedup 1.0000x reference)
//
#include <hip/hip_runtime.h>
#include <math.h>

// Sizes (fixed by the reference)
#define BATCH 16384
#define K_DIM 3072

typedef float  f32x4  __attribute__((ext_vector_type(4)));
typedef __bf16 bf16x8 __attribute__((ext_vector_type(8)));
typedef unsigned int u32x2 __attribute__((ext_vector_type(2)));

__device__ __forceinline__ unsigned short f2bf(float f) {
  union { float f; unsigned u; } v; v.f = f;
  unsigned u = v.u + 0x7fffu + ((v.u >> 16) & 1u);   // RNE
  return (unsigned short)(u >> 16);
}

// fp32x8 -> bf16x8, RNE (same rounding as f2bf)
__device__ __forceinline__ bf16x8 cvt8(f32x4 lo, f32x4 hi) {
  bf16x8 r;
  r[0] = (__bf16)lo[0]; r[1] = (__bf16)lo[1]; r[2] = (__bf16)lo[2]; r[3] = (__bf16)lo[3];
  r[4] = (__bf16)hi[0]; r[5] = (__bf16)hi[1]; r[6] = (__bf16)hi[2]; r[7] = (__bf16)hi[3];
  return r;
}

// async global -> LDS DMA, 16 bytes per lane (zero VGPR cost, counts vmcnt)
__device__ __forceinline__ void gld16(const void* g, void* l) {
  __builtin_amdgcn_global_load_lds(
      (const __attribute__((address_space(1))) unsigned int*)g,
      (__attribute__((address_space(3))) unsigned int*)l, 16, 0, 0);
}

// ---------------- kernel 1: w1 fp32 -> bf16 (128*3072 elements) + accs zero ----------------
__global__ void cvt_w1_kernel(const float* __restrict__ w1, unsigned short* __restrict__ o,
                              float* __restrict__ accs) {
  if (blockIdx.x == 0 && threadIdx.x < 16) accs[threadIdx.x] = 0.f;
  int i = blockIdx.x * 256 + threadIdx.x;          // 98304 float4s
  f32x4 v = ((const f32x4*)w1)[i];
  u32x2 p = { (unsigned)f2bf(v.x) | ((unsigned)f2bf(v.y) << 16),
              (unsigned)f2bf(v.z) | ((unsigned)f2bf(v.w) << 16) };
  ((u32x2*)o)[i] = p;
}

// ---------------- kernel 2: fused router + GEMM + MoE epilogue ----------------
// BM=16 rows/block, 1024 blocks x 256 threads, LDS = 40960 B exactly
// -> 4 blocks/CU resident (16 waves/CU). TLP between unsynchronized co-resident
// blocks hides the drain latency (m97/m114 mechanism). Per phase (BK=64):
// STAGE(next tile, 5 DMA loads/thread) -> vmcnt(5) (current tile landed, next
// stays in flight) -> barrier -> COMPUTE -> barrier. Converged control flow
// throughout. Source-side XOR swizzle on DMA + same XOR on ds_read.
__global__ __launch_bounds__(256, 4) void moe_main_kernel(
    const float* __restrict__ x, const unsigned short* __restrict__ w1bf,
    const float* __restrict__ b1, const float* __restrict__ w2,
    const float* __restrict__ b2, const float* __restrict__ w3,
    const float* __restrict__ b3, const float* __restrict__ psqt,
    const float* __restrict__ st, const float* __restrict__ rw,
    const float* __restrict__ rb, float* __restrict__ out,
    float* __restrict__ accs) {
  // buffer c at [c*20480, (c+1)*20480): A 4096 B then B 16384 B
  __shared__ __align__(16) unsigned char stage_sm[40960];   // EXACTLY 40960: 4 blocks/CU

  const int tid = threadIdx.x;
  const int bm  = blockIdx.x;
  float* Cl  = (float*)stage_sm;                    // epilogue overlay (8448 B)
  float* w2s = (float*)(stage_sm + 8448);           // epilogue overlay (30848 B)

  // ---- wave/lane geometry ----
  const int lane = tid & 63, wv = tid >> 6;
  const int l16 = lane & 15, lq = lane >> 4;
  const int cb = wv << 1;             // first of 2 col-tiles (of 8)

  // ---- DMA staging addresses (source-swizzled, LDS linear) ----
  // A: f32 [16 rows][64 k] = 4 KB; slot tid holds 16B-block (tid&15)^(row&7)
  const float* gA; int lA;
  {
    int row = tid >> 4, blk = tid & 15;
    gA = x + (size_t)(bm * 16 + row) * K_DIM + ((blk ^ (row & 7)) << 2);
    lA = tid << 4;
  }
  // B: bf16 [128 rows][64 k] = 16 KB; slot idx holds 16B-block (idx&7)^(row&7)
  const unsigned short* gB[4]; int lB[4];
#pragma unroll
  for (int r = 0; r < 4; ++r) {
    int idx = r * 256 + tid; int row = idx >> 3; int blk = idx & 7;
    gB[r] = w1bf + (size_t)row * K_DIM + ((blk ^ (row & 7)) << 3);
    lB[r] = idx << 4;
  }

  // ---- LDS read offsets (same XOR as the writers) ----
  int aoff[2], boff[2][2];
#pragma unroll
  for (int ks = 0; ks < 2; ++ks) {
    aoff[ks] = l16 * 256 + (((ks * 8 + lq * 2) ^ (l16 & 7)) << 4);
#pragma unroll
    for (int cc = 0; cc < 2; ++cc) {
      int o = (cb + cc) * 16 + l16;
      boff[ks][cc] = o * 128 + (((lq + ks * 4) ^ (l16 & 7)) << 4);
    }
  }

#define STAGE(C, KT) do {                                                  \
    unsigned char* ab_ = stage_sm + (C) * 20480;                           \
    unsigned char* bb_ = ab_ + 4096;                                       \
    gld16(gA + (KT) * 64, ab_ + lA);                                       \
    gld16(gB[0] + (KT) * 64, bb_ + lB[0]);                                 \
    gld16(gB[1] + (KT) * 64, bb_ + lB[1]);                                 \
    gld16(gB[2] + (KT) * 64, bb_ + lB[2]);                                 \
    gld16(gB[3] + (KT) * 64, bb_ + lB[3]);                                 \
  } while (0)

#define COMPUTE(C) do {                                                    \
    const unsigned char* ab_ = stage_sm + (C) * 20480;                     \
    const unsigned char* bb_ = ab_ + 4096;                                 \
    _Pragma("unroll")                                                      \
    for (int ks = 0; ks < 2; ++ks) {                                       \
      f32x4 a0 = *(const f32x4*)(ab_ + aoff[ks]);                          \
      f32x4 a1 = *(const f32x4*)(ab_ + (aoff[ks] ^ 16));                   \
      bf16x8 af = cvt8(a0, a1);                                            \
      _Pragma("unroll")                                                    \
      for (int cc = 0; cc < 2; ++cc) {                                     \
        bf16x8 bfv = *(const bf16x8*)(bb_ + boff[ks][cc]);                 \
        acc[cc] = __builtin_amdgcn_mfma_f32_16x16x32_bf16(af, bfv,         \
                                                          acc[cc], 0,0,0); \
      }                                                                    \
    }                                                                      \
  } while (0)

  f32x4 acc[2];
  acc[0] = (f32x4){0.f, 0.f, 0.f, 0.f};
  acc[1] = (f32x4){0.f, 0.f, 0.f, 0.f};

  // issue tile 0 now; it flies while the router math runs
  STAGE(0, 0);

  // ---- inline router: thread = (row bl, expert e), fp64 for argmax parity ----
  // (global atomics below issue BEFORE STAGE(1,1), so every later vmcnt(5)
  //  only ever under-counts conservatively — safe.)
  float logp_self = 0.f;
  int   rowEidx   = 0;
  if (tid < 128) {
    const int bl = tid >> 3, e = tid & 7;
    const int bg = bm * 16 + bl;
    const float* xrow  = x + (size_t)bg * K_DIM;
    const float* rwrow = rw + e * 64;
    double lr = (double)rb[e];
#pragma unroll
    for (int c4 = 0; c4 < 8; ++c4) {
      f32x4 xv  = *(const f32x4*)(xrow + c4 * 4);
      f32x4 wvv = *(const f32x4*)(rwrow + c4 * 4);
#pragma unroll
      for (int j = 0; j < 4; ++j) lr = fma((double)xv[j], (double)wvv[j], lr);
    }
#pragma unroll
    for (int c4 = 0; c4 < 8; ++c4) {
      f32x4 xv  = *(const f32x4*)(xrow + 1536 + c4 * 4);
      f32x4 wvv = *(const f32x4*)(rwrow + 32 + c4 * 4);
#pragma unroll
      for (int j = 0; j < 4; ++j) lr = fma((double)xv[j], (double)wvv[j], lr);
    }
    // argmax over the 8 expert lanes (first-max-wins, jnp.argmax semantics)
    double mx = lr; int mi = e;
#pragma unroll
    for (int m = 1; m < 8; m <<= 1) {
      double ov = __shfl_xor(mx, m);
      int    oi = __shfl_xor(mi, m);
      if (ov > mx || (ov == mx && oi < mi)) { mx = ov; mi = oi; }
    }
    double ssum = exp(lr - mx);
#pragma unroll
    for (int m = 1; m < 8; m <<= 1) ssum += __shfl_xor(ssum, m);
    const double lse = mx + log(ssum);
    logp_self = (float)(lr - lse);
    rowEidx   = mi;

    if (e == 0) atomicAdd(&accs[rowEidx], 1.0f);     // expert histogram
    float zc = (e == 0) ? (float)(lse * lse) : 0.f;
#pragma unroll
    for (int m = 1; m < 64; m <<= 1) zc += __shfl_xor(zc, m);
    if (lane == 0) atomicAdd(&accs[8], zc);          // z-loss partial
  }

  // ---- K-loop: 48 tiles, 2-deep, counted vmcnt drain, converged barriers ----
#pragma unroll 1
  for (int t = 0; t < 47; ++t) {
    STAGE((t + 1) & 1, t + 1);
    asm volatile("s_waitcnt vmcnt(5)" ::: "memory");   // tile t landed
    __builtin_amdgcn_s_barrier();
    COMPUTE(t & 1);
    __builtin_amdgcn_s_barrier();
  }
  asm volatile("s_waitcnt vmcnt(0)" ::: "memory");     // tile 47 landed
  __builtin_amdgcn_s_barrier();
  COMPUTE(1);

  // ---- join: C -> LDS + w2 restage (overlay dead staging buffers) ----
  __syncthreads();                                     // all K-loop LDS reads done
#pragma unroll
  for (int cc = 0; cc < 2; ++cc)
#pragma unroll
    for (int r = 0; r < 4; ++r)
      Cl[(lq * 4 + r) * 132 + (cb + cc) * 16 + l16] = acc[cc][r];
  for (int i = tid; i < 7680; i += 256) {              // w2 -> [e][i*32+o]
    int ee = i / 960; int rr = i - ee * 960; int o = rr / 30; int ii = rr - o * 30;
    w2s[ee * 964 + ii * 32 + o] = w2[i];
  }
  __syncthreads();

  // ---------------- epilogue: one thread per (sample, expert) ----------------
  if (tid < 128) {
    const int bl = tid >> 3, e = tid & 7;
    const int bg = bm * 16 + bl;

    float a[16];
    {
      const float* crow = Cl + bl * 132 + e * 16;
      const float* b1p  = b1 + e * 16;
#pragma unroll
      for (int j = 0; j < 16; ++j) a[j] = crow[j] + b1p[j];
    }

    float h[30];
#pragma unroll
    for (int j = 0; j < 15; ++j) {
      float v = a[j];
      h[j]      = fminf(fmaxf(v * v * (255.0f / 256.0f), 0.f), 1.f);
      h[15 + j] = fminf(fmaxf(v, 0.f), 1.f);
    }

    float acc2[32];
    {
      const f32x4* b2v = (const f32x4*)(b2 + e * 32);
#pragma unroll
      for (int o4 = 0; o4 < 8; ++o4) {
        f32x4 tv = b2v[o4];
        acc2[o4 * 4 + 0] = tv.x; acc2[o4 * 4 + 1] = tv.y;
        acc2[o4 * 4 + 2] = tv.z; acc2[o4 * 4 + 3] = tv.w;
      }
    }
    const f32x4* wrow = (const f32x4*)&w2s[e * 964];
#pragma unroll
    for (int i = 0; i < 30; ++i) {
      float hv = h[i];
#pragma unroll
      for (int o4 = 0; o4 < 8; ++o4) {
        f32x4 wq = wrow[i * 8 + o4];
        acc2[o4 * 4 + 0] += hv * wq.x;
        acc2[o4 * 4 + 1] += hv * wq.y;
        acc2[o4 * 4 + 2] += hv * wq.z;
        acc2[o4 * 4 + 3] += hv * wq.w;
      }
    }

    float outv = b3[e] + a[15];  // b3 + skip
    {
      const f32x4* w3v = (const f32x4*)(w3 + e * 32);
#pragma unroll
      for (int o4 = 0; o4 < 8; ++o4) {
        f32x4 tv = w3v[o4];
        outv += fminf(fmaxf(acc2[o4 * 4 + 0], 0.f), 1.f) * tv.x;
        outv += fminf(fmaxf(acc2[o4 * 4 + 1], 0.f), 1.f) * tv.y;
        outv += fminf(fmaxf(acc2[o4 * 4 + 2], 0.f), 1.f) * tv.z;
        outv += fminf(fmaxf(acc2[o4 * 4 + 3], 0.f), 1.f) * tv.w;
      }
    }

    // probe softmax over the 8 experts (lanes e=0..7 within each group of 8)
    float eo  = (outv + psqt[bg]) * 600.0f;
    float dd  = eo - st[bg];
    float err = dd * dd;
    float mn = err;
    mn = fminf(mn, __shfl_xor(mn, 1));
    mn = fminf(mn, __shfl_xor(mn, 2));
    mn = fminf(mn, __shfl_xor(mn, 4));
    float wexp = expf(-(err - mn));
    float ss = wexp;
    ss += __shfl_xor(ss, 1); ss += __shfl_xor(ss, 2); ss += __shfl_xor(ss, 4);
    float pt  = wexp / ss;
    float lpt = logf(fmaxf(pt, 1e-30f));
    float term = pt * (lpt - logp_self);
    term += __shfl_xor(term, 1); term += __shfl_xor(term, 2); term += __shfl_xor(term, 4);
    float c1 = (e == 0) ? term : 0.f;
    c1 += __shfl_xor(c1, 8); c1 += __shfl_xor(c1, 16); c1 += __shfl_xor(c1, 32);
    if (lane == 0) atomicAdd(&accs[9], c1);          // probe-loss partial

    if (e == rowEidx) out[bg] = outv;  // gating multiplier is exactly 1.0 in fwd
  }
#undef STAGE
#undef COMPUTE
}

// ---------------- kernel 3: finalize scalar ----------------
__global__ void finalize_kernel(const float* __restrict__ accs, float* __restrict__ out) {
  if (threadIdx.x == 0) {
    float fsum = 0.f;
    for (int e = 0; e < 8; ++e) {
      float frac = accs[e] * (1.0f / 16384.0f);
      float f = fmaxf(0.05f - frac, 0.f);
      float c = fmaxf(frac - 0.5f, 0.f);
      fsum += f * f + c * c;
    }
    float aux   = fsum * 0.125f;             // floor_loss + cap_loss (each mean over E)
    float z     = accs[8] * (1.0f / 16384.0f);
    float probe = accs[9] * (1.0f / 16384.0f);
    out[BATCH] = 0.01f * aux + 0.001f * z + 0.01f * probe;
  }
}

extern "C" void kernel_launch(void* const* d_in, const int* in_sizes, int n_in,
                              void* d_out, int out_size, void* d_ws, size_t ws_size,
                              hipStream_t stream) {
  const float* x    = (const float*)d_in[0];
  // d_in[1] = ls_indices: unused (TEACHER_ALPHA == 0)
  const float* psqt = (const float*)d_in[2];
  const float* st   = (const float*)d_in[3];
  const float* rw   = (const float*)d_in[4];
  const float* rb   = (const float*)d_in[5];
  const float* w1   = (const float*)d_in[6];
  const float* b1   = (const float*)d_in[7];
  const float* w2   = (const float*)d_in[8];
  const float* b2   = (const float*)d_in[9];
  const float* w3   = (const float*)d_in[10];
  const float* b3   = (const float*)d_in[11];
  float* out = (float*)d_out;

  unsigned short* w1bf = (unsigned short*)d_ws;                 // 786432 B
  float* accs = (float*)((char*)d_ws + 786432);                 // 16 floats

  cvt_w1_kernel<<<384, 256, 0, stream>>>(w1, w1bf, accs);
  moe_main_kernel<<<1024, 256, 0, stream>>>(x, w1bf, b1, w2, b2, w3, b3,
                                            psqt, st, rw, rb, out, accs);
  finalize_kernel<<<1, 1, 0, stream>>>(accs, out);
}